// Round 11
// baseline (219.843 us; speedup 1.0000x reference)
//
#include <hip/hip_runtime.h>
#include <stdint.h>

#define NN 50000
#define NB 196              // ceil(NN/256)
#define NTILES 782          // ceil(NN/64) gemm tiles
#define NEG_SLOPE 0.2f
#define WTS 136             // padded W^T row stride (u16)

// output layout (element offsets)
#define IXZ_OFF    (NN * 64)
#define SKL_OFF    (NN * 64 + NN)
#define MEAN_OFF   (NN * 64 + NN + 1)
#define STD_OFF    (MEAN_OFF + NN * 64)

typedef unsigned int u32;
typedef unsigned short u16;
typedef unsigned char u8;
typedef __attribute__((ext_vector_type(8))) short short8;
typedef __attribute__((ext_vector_type(4))) float f32x4;
typedef __attribute__((ext_vector_type(2))) float f32x2;

__device__ __forceinline__ float bf2f(u16 s) { return __uint_as_float(((u32)s) << 16); }
__device__ __forceinline__ u16 f2bf(float f) {
    u32 u = __float_as_uint(f);
    u += 0x7FFFu + ((u >> 16) & 1u);   // RNE
    return (u16)(u >> 16);
}
__device__ __forceinline__ float lo16(u32 u) { return __uint_as_float(u << 16); }
__device__ __forceinline__ float hi16(u32 u) { return __uint_as_float(u & 0xFFFF0000u); }
__device__ __forceinline__ float softplusf(float x) {
    return fmaxf(x, 0.f) + log1pf(expf(-fabsf(x)));
}
__device__ __forceinline__ void stout(void* o, long long idx, float v, bool f32) {
    if (f32) ((float*)o)[idx] = v;
    else     ((u16*)o)[idx]   = f2bf(v);
}
__device__ __forceinline__ int wscan_incl(int v, int lane) {
#pragma unroll
    for (int off = 1; off < 64; off <<= 1) {
        int u = __shfl_up(v, off);
        if (lane >= off) v += u;
    }
    return v;
}

// dtype detect: bf16 data -> low u16 of dwords has sane bf16 exponent
__device__ __forceinline__ bool detect_f32_block(const u32* __restrict__ xw,
                                                 int* lflag)
{
    const int t = threadIdx.x;
    if (t < 64) {
        u32 wrd = xw[t];
        u32 e = (wrd >> 7) & 0xFF;
        bool plaus = (e >= 0x60 && e <= 0x85);
        unsigned long long b = __ballot(plaus);
        if (t == 0) *lflag = (__popcll(b) < 32) ? 1 : 0;
    }
    __syncthreads();
    return *lflag != 0;
}

// ---------------------------------------------------------------------------
// k_wt: 64 blocks. Zero counts+cursor+done; blocks 0..7 transpose W into the
// padded global W^T image (bf16).
// ---------------------------------------------------------------------------
__global__ __launch_bounds__(256) void k_wt(const void* __restrict__ xv,
                                            const void* __restrict__ wv_,
                                            u16* __restrict__ wtg,
                                            int* __restrict__ zbase)
{
    __shared__ int lflag;
    const bool f32 = detect_f32_block((const u32*)xv, &lflag);
    const int t = threadIdx.x;

    for (int i = blockIdx.x * 256 + t; i < 2 * NN + 1; i += 64 * 256)
        zbase[i] = 0;

    if (blockIdx.x < 8) {
        const int k = blockIdx.x * 16 + (t >> 4);
        const int cq = t & 15;
        u16 v[8];
        if (f32) {
            const float* w = (const float*)wv_;
            float4 a = *(const float4*)(w + k * 128 + cq * 8);
            float4 b = *(const float4*)(w + k * 128 + cq * 8 + 4);
            v[0] = f2bf(a.x); v[1] = f2bf(a.y); v[2] = f2bf(a.z); v[3] = f2bf(a.w);
            v[4] = f2bf(b.x); v[5] = f2bf(b.y); v[6] = f2bf(b.z); v[7] = f2bf(b.w);
        } else {
            const u16* w = (const u16*)wv_;
            uint4 u = *(const uint4*)(w + k * 128 + cq * 8);
            v[0] = (u16)(u.x & 0xFFFF); v[1] = (u16)(u.x >> 16);
            v[2] = (u16)(u.y & 0xFFFF); v[3] = (u16)(u.y >> 16);
            v[4] = (u16)(u.z & 0xFFFF); v[5] = (u16)(u.z >> 16);
            v[6] = (u16)(u.w & 0xFFFF); v[7] = (u16)(u.w >> 16);
        }
#pragma unroll
        for (int j = 0; j < 8; j++)
            wtg[(cq * 8 + j) * WTS + k] = v[j];
    }
}

// ---------------------------------------------------------------------------
// k_cnt: dst-degree histogram (separate for profile visibility)
// ---------------------------------------------------------------------------
__global__ __launch_bounds__(256) void k_cnt(const int* __restrict__ dst,
                                             int* __restrict__ counts, int E)
{
    int e = blockIdx.x * 256 + threadIdx.x;
    if (e < E) atomicAdd(&counts[dst[e]], 1);
}

// ---------------------------------------------------------------------------
// MFMA GEMM: h = x @ W -> fp8 e4m3 hb. Wave = 16 nodes x 128 ch.
// B-frags straight from the global (L2-hot) W^T image — no LDS staging, no
// cross-wave barriers. LDS = per-wave repack buffer only (17 KB/block).
// ---------------------------------------------------------------------------
__global__ __launch_bounds__(256) void k_gemm(
    const void* __restrict__ xv, const u16* __restrict__ wtg,
    const void* __restrict__ attv, u8* __restrict__ hb,
    float* __restrict__ ai, float* __restrict__ aj)
{
    __shared__ __align__(16) u16 rp[4][16 * WTS];   // 17408 B
    __shared__ int lflag;
    const bool f32 = detect_f32_block((const u32*)xv, &lflag);
    const int tid = threadIdx.x;

    const int w = tid >> 6, L = tid & 63;
    const int q = L >> 4, c15 = L & 15;
    const int nb16 = blockIdx.x * 64 + w * 16;

    // A fragments: A[m=c15][k=q*8+j]
    short8 afr[4];
    {
        int nrow = nb16 + c15; if (nrow > NN - 1) nrow = NN - 1;
        if (f32) {
            const float* xp = (const float*)xv + (size_t)nrow * 128 + q * 8;
#pragma unroll
            for (int ks = 0; ks < 4; ks++) {
                float4 a = *(const float4*)(xp + ks * 32);
                float4 b = *(const float4*)(xp + ks * 32 + 4);
                union { short8 s; u16 e[8]; } u;
                u.e[0] = f2bf(a.x); u.e[1] = f2bf(a.y); u.e[2] = f2bf(a.z); u.e[3] = f2bf(a.w);
                u.e[4] = f2bf(b.x); u.e[5] = f2bf(b.y); u.e[6] = f2bf(b.z); u.e[7] = f2bf(b.w);
                afr[ks] = u.s;
            }
        } else {
            const u16* xp = (const u16*)xv + (size_t)nrow * 128 + q * 8;
#pragma unroll
            for (int ks = 0; ks < 4; ks++)
                afr[ks] = *(const short8*)(xp + ks * 32);
        }
    }

    // 8 column tiles x 4 K-steps, B from global W^T image
    f32x4 acc[8];
#pragma unroll
    for (int t = 0; t < 8; t++) {
        acc[t] = (f32x4){0.f, 0.f, 0.f, 0.f};
        const u16* bp = wtg + (16 * t + c15) * WTS + q * 8;
#pragma unroll
        for (int ks = 0; ks < 4; ks++) {
            short8 bfr = *(const short8*)(bp + ks * 32);
            acc[t] = __builtin_amdgcn_mfma_f32_16x16x32_bf16(afr[ks], bfr, acc[t], 0, 0, 0);
        }
    }

    // attention scalars
    float ati[8], atj[8];
#pragma unroll
    for (int t = 0; t < 8; t++) {
        int p = (t >> 1) * 64 + (t & 1) * 16 + c15;
        if (f32) {
            ati[t] = ((const float*)attv)[p];
            atj[t] = ((const float*)attv)[p + 32];
        } else {
            ati[t] = bf2f(((const u16*)attv)[p]);
            atj[t] = bf2f(((const u16*)attv)[p + 32]);
        }
    }
#pragma unroll
    for (int r = 0; r < 4; r++) {
        int node = nb16 + q * 4 + r;
#pragma unroll
        for (int h = 0; h < 4; h++) {
            float pi = acc[2 * h][r] * ati[2 * h] + acc[2 * h + 1][r] * ati[2 * h + 1];
            float pj = acc[2 * h][r] * atj[2 * h] + acc[2 * h + 1][r] * atj[2 * h + 1];
            pi += __shfl_xor(pi, 1); pj += __shfl_xor(pj, 1);
            pi += __shfl_xor(pi, 2); pj += __shfl_xor(pj, 2);
            pi += __shfl_xor(pi, 4); pj += __shfl_xor(pj, 4);
            pi += __shfl_xor(pi, 8); pj += __shfl_xor(pj, 8);
            if (c15 == 0 && node < NN) { ai[node * 4 + h] = pi; aj[node * 4 + h] = pj; }
        }
    }

    // repack in wave-private LDS (no barrier needed), fp8-convert, store 8B
    u16* myls = rp[w];
#pragma unroll
    for (int t = 0; t < 8; t++)
#pragma unroll
        for (int r = 0; r < 4; r++)
            myls[(q * 4 + r) * WTS + 16 * t + c15] = f2bf(acc[t][r]);
#pragma unroll
    for (int v = 0; v < 4; v++) {
        int idx = v * 64 + L;
        int nrow = idx >> 4, c8 = idx & 15;
        int node = nb16 + nrow;
        uint4 t16 = *(const uint4*)(myls + nrow * WTS + c8 * 8);
        float f0 = lo16(t16.x), f1 = hi16(t16.x);
        float f2 = lo16(t16.y), f3 = hi16(t16.y);
        float f4 = lo16(t16.z), f5 = hi16(t16.z);
        float f6 = lo16(t16.w), f7 = hi16(t16.w);
        u32 lo = 0, hi = 0;
        lo = __builtin_amdgcn_cvt_pk_fp8_f32(f0, f1, lo, false);
        lo = __builtin_amdgcn_cvt_pk_fp8_f32(f2, f3, lo, true);
        hi = __builtin_amdgcn_cvt_pk_fp8_f32(f4, f5, hi, false);
        hi = __builtin_amdgcn_cvt_pk_fp8_f32(f6, f7, hi, true);
        if (node < NN) {
            uint2 o; o.x = lo; o.y = hi;
            *(uint2*)(hb + (size_t)node * 128 + c8 * 8) = o;
        }
    }
}

// ---------------------------------------------------------------------------
// k_scan1: local prefix + blocksum; LAST block scans blocksums -> sboff_g
// ---------------------------------------------------------------------------
__global__ __launch_bounds__(256) void k_scan1(const int* __restrict__ counts,
                                               int* __restrict__ lexcl,
                                               int* __restrict__ blocksum,
                                               int* __restrict__ done,
                                               int* __restrict__ sboff_g)
{
    __shared__ int wsum[4];
    __shared__ int lastf;
    const int t = threadIdx.x, lane = t & 63, wv = t >> 6;
    const int i = blockIdx.x * 256 + t;
    int c = (i < NN) ? counts[i] : 0;
    int inc = wscan_incl(c, lane);
    if (lane == 63) wsum[wv] = inc;
    __syncthreads();
    int add = 0;
#pragma unroll
    for (int k = 0; k < 3; k++) if (k < wv) add += wsum[k];
    inc += add;
    if (i < NN) lexcl[i] = inc - c;
    if (t == 255) {
        blocksum[blockIdx.x] = inc;
        __threadfence();
        lastf = (atomicAdd(done, 1) == NB - 1) ? 1 : 0;
    }
    __syncthreads();
    if (lastf) {
        __threadfence();
        int c2 = (t < NB) ? blocksum[t] : 0;
        int inc2 = wscan_incl(c2, lane);
        if (lane == 63) wsum[wv] = inc2;
        __syncthreads();
        int add2 = 0;
#pragma unroll
        for (int k = 0; k < 3; k++) if (k < wv) add2 += wsum[k];
        sboff_g[t] = inc2 + add2 - c2;
    }
}

// ---------------------------------------------------------------------------
// k_fill: CSR scatter using global sboff_g
// ---------------------------------------------------------------------------
__global__ __launch_bounds__(256) void k_fill(
    const int* __restrict__ ei, const int* __restrict__ lexcl,
    const int* __restrict__ sboff_g, int* __restrict__ cursor,
    int* __restrict__ perm_src, int E)
{
    int e = blockIdx.x * 256 + threadIdx.x;
    if (e >= E) return;
    int d = ei[E + e];                    // dst
    int pos = sboff_g[d >> 8] + lexcl[d] + atomicAdd(&cursor[d], 1);
    perm_src[pos] = ei[e];                // src
}

// ---------------------------------------------------------------------------
// Aggregation + finalize: 16 threads/node, lane l -> channels 8l..8l+7,
// head = l>>2. Software-pipelined: h-loads issue from pre-resident indices;
// next pair's perm_src+aj prefetch overlaps the exp/FMA compute.
// ---------------------------------------------------------------------------
__global__ __launch_bounds__(256) void k_agg(
    const int* __restrict__ lexcl, const int* __restrict__ sboff_g,
    const int* __restrict__ counts, const int* __restrict__ perm_src,
    const float* __restrict__ ai, const float* __restrict__ aj,
    const u8* __restrict__ hb, const void* __restrict__ biasv,
    const void* __restrict__ xv, void* __restrict__ outv)
{
    __shared__ int lflag;
    const bool f32 = detect_f32_block((const u32*)xv, &lflag);
    const int t = blockIdx.x * 256 + threadIdx.x;
    const int node = t >> 4;
    const int l = t & 15;
    const int head = l >> 2;
    const int cc0 = (l & 3) << 3;

    const int rs = sboff_g[node >> 8] + lexcl[node];
    const int re = rs + counts[node];
    const float ain = ai[node * 4 + head];
    const u8* hl8 = hb + l * 8;

    float dsum = 0.f;
    float a0 = 0.f, a1 = 0.f, a2 = 0.f, a3 = 0.f;
    float a4 = 0.f, a5 = 0.f, a6 = 0.f, a7 = 0.f;

    int i = rs;
    int sA = 0, sB = 0;
    float ajA = 0.f, ajB = 0.f;
    if (i < re)     { sA = perm_src[i];     ajA = aj[sA * 4 + head]; }
    if (i + 1 < re) { sB = perm_src[i + 1]; ajB = aj[sB * 4 + head]; }

    while (i + 1 < re) {
        // issue gather loads for current pair immediately
        uint2 h0 = *(const uint2*)(hl8 + (size_t)sA * 128);
        uint2 h1 = *(const uint2*)(hl8 + (size_t)sB * 128);
        // prefetch next pair (overlaps with compute below)
        int i2 = i + 2;
        int sC = 0, sD = 0; float ajC = 0.f, ajD = 0.f;
        if (i2 < re)     { sC = perm_src[i2];     ajC = aj[sC * 4 + head]; }
        if (i2 + 1 < re) { sD = perm_src[i2 + 1]; ajD = aj[sD * 4 + head]; }
        // softmax numerators
        float x0 = ajA + ain; x0 = x0 > 0.f ? x0 : NEG_SLOPE * x0;
        float x1 = ajB + ain; x1 = x1 > 0.f ? x1 : NEG_SLOPE * x1;
        float e0 = __expf(x0), e1 = __expf(x1);
        // unpack + accumulate
        f32x2 p0 = __builtin_amdgcn_cvt_pk_f32_fp8(h0.x, false);
        f32x2 p1 = __builtin_amdgcn_cvt_pk_f32_fp8(h0.x, true);
        f32x2 p2 = __builtin_amdgcn_cvt_pk_f32_fp8(h0.y, false);
        f32x2 p3 = __builtin_amdgcn_cvt_pk_f32_fp8(h0.y, true);
        f32x2 q0 = __builtin_amdgcn_cvt_pk_f32_fp8(h1.x, false);
        f32x2 q1 = __builtin_amdgcn_cvt_pk_f32_fp8(h1.x, true);
        f32x2 q2 = __builtin_amdgcn_cvt_pk_f32_fp8(h1.y, false);
        f32x2 q3 = __builtin_amdgcn_cvt_pk_f32_fp8(h1.y, true);
        dsum += e0 + e1;
        a0 += e0 * p0.x + e1 * q0.x;  a1 += e0 * p0.y + e1 * q0.y;
        a2 += e0 * p1.x + e1 * q1.x;  a3 += e0 * p1.y + e1 * q1.y;
        a4 += e0 * p2.x + e1 * q2.x;  a5 += e0 * p2.y + e1 * q2.y;
        a6 += e0 * p3.x + e1 * q3.x;  a7 += e0 * p3.y + e1 * q3.y;
        i = i2; sA = sC; sB = sD; ajA = ajC; ajB = ajD;
    }
    if (i < re) {   // tail edge: sA/ajA pre-loaded
        uint2 h0 = *(const uint2*)(hl8 + (size_t)sA * 128);
        float x0 = ajA + ain; x0 = x0 > 0.f ? x0 : NEG_SLOPE * x0;
        float e0 = __expf(x0);
        f32x2 p0 = __builtin_amdgcn_cvt_pk_f32_fp8(h0.x, false);
        f32x2 p1 = __builtin_amdgcn_cvt_pk_f32_fp8(h0.x, true);
        f32x2 p2 = __builtin_amdgcn_cvt_pk_f32_fp8(h0.y, false);
        f32x2 p3 = __builtin_amdgcn_cvt_pk_f32_fp8(h0.y, true);
        dsum += e0;
        a0 += e0 * p0.x; a1 += e0 * p0.y;
        a2 += e0 * p1.x; a3 += e0 * p1.y;
        a4 += e0 * p2.x; a5 += e0 * p2.y;
        a6 += e0 * p3.x; a7 += e0 * p3.y;
    }

    const float inv = 1.f / (dsum + 1e-16f);
    const int cb = head * 32 + cc0;
    float v[8];
    if (f32) {
        const float* bias = (const float*)biasv;
#pragma unroll
        for (int j = 0; j < 8; j++) v[j] = bias[cb + j];
    } else {
        const u16* bias = (const u16*)biasv;
#pragma unroll
        for (int j = 0; j < 8; j++) v[j] = bf2f(bias[cb + j]);
    }
    v[0] += a0 * inv; v[1] += a1 * inv; v[2] += a2 * inv; v[3] += a3 * inv;
    v[4] += a4 * inv; v[5] += a5 * inv; v[6] += a6 * inv; v[7] += a7 * inv;

    float part = 0.f;
    if (cc0 < 16) {
#pragma unroll
        for (int j = 0; j < 8; j++) part += 0.5f * v[j] * v[j];
        long long o = (long long)node * 64 + head * 16 + cc0;
#pragma unroll
        for (int j = 0; j < 8; j++) stout(outv, o + j, v[j], f32);
        long long om = (long long)MEAN_OFF + o;
#pragma unroll
        for (int j = 0; j < 8; j++) stout(outv, om + j, v[j], f32);
    } else {
        long long os = (long long)STD_OFF + (long long)node * 64 + head * 16 + (cc0 - 16);
#pragma unroll
        for (int j = 0; j < 8; j++) {
            float s = softplusf(v[j] - 5.f) + 1e-10f;
            part += -logf(s) + 0.5f * s * s - 0.5f;
            stout(outv, os + j, s, f32);
        }
    }
    part += __shfl_xor(part, 1); part += __shfl_xor(part, 2);
    part += __shfl_xor(part, 4); part += __shfl_xor(part, 8);
    if (l == 0) stout(outv, (long long)IXZ_OFF + node, part * 0.25f, f32);
    if (t == 0) stout(outv, (long long)SKL_OFF, 0.f, f32);
}

// ---------------------------------------------------------------------------
extern "C" void kernel_launch(void* const* d_in, const int* in_sizes, int n_in,
                              void* d_out, int out_size, void* d_ws, size_t ws_size,
                              hipStream_t stream)
{
    const void* x    = d_in[0];
    const int*  ei   = (const int*)d_in[1];
    const void* w    = d_in[2];
    const void* att  = d_in[3];
    const void* bias = d_in[4];
    int E = in_sizes[1] / 2;

    // workspace (~11.3 MB): hb(fp8) | ai | aj | perm_src | counts | cursor |
    //                       done | lexcl | blocksum | sboff_g | wtg
    u8*    hb       = (u8*)d_ws;                       // NN*128 fp8
    float* ai       = (float*)(hb + (size_t)NN * 128);
    float* aj       = ai + NN * 4;
    int*   perm_src = (int*)(aj + NN * 4);             // E
    int*   counts   = perm_src + E;                    // NN
    int*   cursor   = counts + NN;                     // NN
    int*   done     = cursor + NN;                     // 1 (zeroed with counts/cursor)
    int*   lexcl    = done + 1;                        // NN
    int*   blocksum = lexcl + NN;                      // NB
    int*   sboff_g  = blocksum + NB;                   // 256
    u16*   wtg      = (u16*)(((uintptr_t)(sboff_g + 256) + 15) & ~(uintptr_t)15);

    k_wt<<<64, 256, 0, stream>>>(x, w, wtg, counts);
    k_cnt<<<(E + 255) / 256, 256, 0, stream>>>(ei + E, counts, E);
    k_gemm<<<NTILES, 256, 0, stream>>>(x, wtg, att, hb, ai, aj);
    k_scan1<<<NB, 256, 0, stream>>>(counts, lexcl, blocksum, done, sboff_g);
    k_fill<<<(E + 255) / 256, 256, 0, stream>>>(ei, lexcl, sboff_g,
                                                cursor, perm_src, E);
    k_agg<<<(NN * 16) / 256, 256, 0, stream>>>(lexcl, sboff_g, counts,
                                               perm_src, ai, aj, hb,
                                               bias, x, d_out);
}